// Round 5
// baseline (232.850 us; speedup 1.0000x reference)
//
#include <hip/hip_runtime.h>
#include <hip/hip_bf16.h>
#include <stdint.h>

typedef __attribute__((ext_vector_type(8))) short short8;
typedef __attribute__((ext_vector_type(4))) float f32x4;
typedef __attribute__((ext_vector_type(16))) float f32x16;
typedef __attribute__((ext_vector_type(2))) unsigned int uint2u;
typedef __hip_bfloat16 bf16;

#define S_LEN 4096
#define DMODEL 1024
#define NH 16
#define HD 64
// Q pre-scale: 1/sqrt(64) * log2(e)  -> softmax via raw v_exp_f32 (2^x)
#define QSCALE 0.1803368801111f

static __device__ inline uint2 pack4(float4 v) {
  union { uint2 u; bf16 h[4]; } p;
  p.h[0] = (bf16)v.x; p.h[1] = (bf16)v.y; p.h[2] = (bf16)v.z; p.h[3] = (bf16)v.w;
  return p.u;
}

static __device__ inline uint32_t pack2(float a, float b) {
  union { uint32_t u; bf16 h[2]; } p;
  p.h[0] = (bf16)a; p.h[1] = (bf16)b;
  return p.u;
}

// async global->LDS, 16B per lane. Global address is PER-LANE (gather);
// LDS dest = wave-uniform base + lane*16.
static __device__ inline void gload_lds16(const bf16* g, bf16* l) {
  __builtin_amdgcn_global_load_lds(
      (const __attribute__((address_space(1))) unsigned int*)g,
      (__attribute__((address_space(3))) unsigned int*)l, 16, 0, 0);
}

// Rotation layout for 64-wide LDS tiles (row stride 64, no padding): element
// (r,c) lives at r*64 + ((c + 8*(r&7)) & 63). DMA staging lanes fetch a
// rotated global column so async writes land in this layout for free; b128
// fragment reads stay 16B-contiguous and spread bank groups evenly.
static __device__ inline int rot_idx(int r, int c) {
  return r * 64 + ((c + ((r & 7) << 3)) & 63);
}

// ---------------------------------------------------------------------------
// One segmented f32->bf16 conversion kernel for x, w_qkv, w_o.
// ---------------------------------------------------------------------------
__global__ __launch_bounds__(256)
void cvt_all(const float* __restrict__ x, const float* __restrict__ wq,
             const float* __restrict__ wo, bf16* __restrict__ xb,
             bf16* __restrict__ wqb, bf16* __restrict__ wob) {
  const int nx = S_LEN * DMODEL;
  const int nq = 3 * DMODEL * DMODEL;
  const int no = DMODEL * DMODEL;
  int i = (blockIdx.x * 256 + threadIdx.x) * 4;
  if (i < nx) {
    *(uint2*)(xb + i) = pack4(*(const float4*)(x + i));
  } else if (i < nx + nq) {
    int j = i - nx;
    *(uint2*)(wqb + j) = pack4(*(const float4*)(wq + j));
  } else if (i < nx + nq + no) {
    int j = i - nx - nq;
    *(uint2*)(wob + j) = pack4(*(const float4*)(wo + j));
  }
}

// ---------------------------------------------------------------------------
// QKV GEMM (bf16 ops, global_load_lds staging, ROTATION LAYOUT -> conflict-
// free ds_read_b128). Epilogue splits output:
//   cols [0,2048): qkv2[row][col]   (Q cols scaled by QSCALE)
//   cols [2048,3072): V written TRANSPOSED per head: vt[h][d][row]
// ---------------------------------------------------------------------------
__global__ __launch_bounds__(256)
void gemm_qkv(const bf16* __restrict__ A, const bf16* __restrict__ B,
              const float* __restrict__ bias, bf16* __restrict__ qkv2,
              bf16* __restrict__ vt) {
  const int K = DMODEL;
  __shared__ bf16 sA[128 * 64];
  __shared__ bf16 sB[128 * 64];
  const int tid  = threadIdx.x;
  const int lane = tid & 63;
  const int wave = tid >> 6;
  const int wm = wave >> 1, wn = wave & 1;
  const int tileM = blockIdx.y * 128;
  const int tileN = blockIdx.x * 128;

  const int lrow = lane & 15;
  const int quad = lane >> 4;
  const int kq   = quad * 8;

  f32x4 acc[4][4];
#pragma unroll
  for (int i = 0; i < 4; i++)
#pragma unroll
    for (int j = 0; j < 4; j++) acc[i][j] = (f32x4){0.f, 0.f, 0.f, 0.f};

  // staging lane geometry: row-in-chunk + rotated global column
  const int trl = lane >> 3;                          // 0..7
  const int cgl = (((lane & 7) - trl) & 7) << 3;      // rotated col, mult of 8
  const bf16* aP[4];
  const bf16* bP[4];
#pragma unroll
  for (int c = 0; c < 4; c++) {
    int ch = wave * 4 + c;
    aP[c] = A + (size_t)(tileM + ch * 8 + trl) * K + cgl;
    bP[c] = B + (size_t)(tileN + ch * 8 + trl) * K + cgl;
  }

  for (int k0 = 0; k0 < K; k0 += 64) {
    __syncthreads();
#pragma unroll
    for (int c = 0; c < 4; c++) {
      int ch = wave * 4 + c;
      gload_lds16(aP[c] + k0, sA + ch * 512);
      gload_lds16(bP[c] + k0, sB + ch * 512);
    }
    __syncthreads();
#pragma unroll
    for (int ks = 0; ks < 2; ks++) {
      short8 afrag[4], bfrag[4];
#pragma unroll
      for (int mi = 0; mi < 4; mi++)
        afrag[mi] = *(const short8*)(sA + rot_idx(wm * 64 + mi * 16 + lrow, ks * 32 + kq));
#pragma unroll
      for (int ni = 0; ni < 4; ni++)
        bfrag[ni] = *(const short8*)(sB + rot_idx(wn * 64 + ni * 16 + lrow, ks * 32 + kq));
#pragma unroll
      for (int mi = 0; mi < 4; mi++)
#pragma unroll
        for (int ni = 0; ni < 4; ni++)
          acc[mi][ni] = __builtin_amdgcn_mfma_f32_16x16x32_bf16(afrag[mi], bfrag[ni], acc[mi][ni], 0, 0, 0);
    }
  }

#pragma unroll
  for (int ni = 0; ni < 4; ni++) {
    int col = tileN + wn * 64 + ni * 16 + lrow;
    float bv = bias[col];
    if (col < 2 * DMODEL) {
      float sc = (col < DMODEL) ? QSCALE : 1.0f;
#pragma unroll
      for (int mi = 0; mi < 4; mi++) {
        int row0 = tileM + wm * 64 + mi * 16 + quad * 4;
#pragma unroll
        for (int r = 0; r < 4; r++)
          qkv2[(size_t)(row0 + r) * 2048 + col] = (bf16)((acc[mi][ni][r] + bv) * sc);
      }
    } else {
      int cc = col - 2 * DMODEL;
      int hh = cc >> 6, dd = cc & 63;
      bf16* vrow = vt + ((size_t)(hh * 64 + dd)) * S_LEN;
#pragma unroll
      for (int mi = 0; mi < 4; mi++) {
        int row0 = tileM + wm * 64 + mi * 16 + quad * 4;
        float4 v = {acc[mi][ni][0] + bv, acc[mi][ni][1] + bv,
                    acc[mi][ni][2] + bv, acc[mi][ni][3] + bv};
        *(uint2*)(vrow + row0) = pack4(v);
      }
    }
  }
}

// ---------------------------------------------------------------------------
// O-projection GEMM (bf16 ops -> f32 out), 128x64 tiles, rotation layout.
// ---------------------------------------------------------------------------
__global__ __launch_bounds__(256)
void gemm_oproj(const bf16* __restrict__ A, const bf16* __restrict__ B,
                const float* __restrict__ bias, float* __restrict__ C) {
  const int K = DMODEL, N = DMODEL;
  __shared__ bf16 sA[128 * 64];
  __shared__ bf16 sB[64 * 64];
  const int tid  = threadIdx.x;
  const int lane = tid & 63;
  const int wave = tid >> 6;
  const int wm = wave >> 1, wn = wave & 1;     // wave tile: 64 rows x 32 cols
  const int tileM = blockIdx.y * 128;          // gridDim.y = 32
  const int tileN = blockIdx.x * 64;           // gridDim.x = 16

  const int lrow = lane & 15;
  const int quad = lane >> 4;
  const int kq   = quad * 8;

  f32x4 acc[4][2];
#pragma unroll
  for (int i = 0; i < 4; i++)
#pragma unroll
    for (int j = 0; j < 2; j++) acc[i][j] = (f32x4){0.f, 0.f, 0.f, 0.f};

  const int trl = lane >> 3;
  const int cgl = (((lane & 7) - trl) & 7) << 3;
  const bf16* aP[4];
  const bf16* bP[2];
#pragma unroll
  for (int c = 0; c < 4; c++) {
    int ch = wave * 4 + c;
    aP[c] = A + (size_t)(tileM + ch * 8 + trl) * K + cgl;
  }
#pragma unroll
  for (int c = 0; c < 2; c++) {
    int ch = wave * 2 + c;
    bP[c] = B + (size_t)(tileN + ch * 8 + trl) * K + cgl;
  }

  for (int k0 = 0; k0 < K; k0 += 64) {
    __syncthreads();
#pragma unroll
    for (int c = 0; c < 4; c++)
      gload_lds16(aP[c] + k0, sA + (wave * 4 + c) * 512);
#pragma unroll
    for (int c = 0; c < 2; c++)
      gload_lds16(bP[c] + k0, sB + (wave * 2 + c) * 512);
    __syncthreads();
#pragma unroll
    for (int ks = 0; ks < 2; ks++) {
      short8 afrag[4], bfrag[2];
#pragma unroll
      for (int mi = 0; mi < 4; mi++)
        afrag[mi] = *(const short8*)(sA + rot_idx(wm * 64 + mi * 16 + lrow, ks * 32 + kq));
#pragma unroll
      for (int ni = 0; ni < 2; ni++)
        bfrag[ni] = *(const short8*)(sB + rot_idx(wn * 32 + ni * 16 + lrow, ks * 32 + kq));
#pragma unroll
      for (int mi = 0; mi < 4; mi++)
#pragma unroll
        for (int ni = 0; ni < 2; ni++)
          acc[mi][ni] = __builtin_amdgcn_mfma_f32_16x16x32_bf16(afrag[mi], bfrag[ni], acc[mi][ni], 0, 0, 0);
    }
  }

#pragma unroll
  for (int ni = 0; ni < 2; ni++) {
    int col = tileN + wn * 32 + ni * 16 + lrow;
    float bv = bias[col];
#pragma unroll
    for (int mi = 0; mi < 4; mi++) {
      int row0 = tileM + wm * 64 + mi * 16 + quad * 4;
#pragma unroll
      for (int r = 0; r < 4; r++)
        C[(size_t)(row0 + r) * N + col] = acc[mi][ni][r] + bv;
    }
  }
}

// ---------------------------------------------------------------------------
// Fallback QKV GEMM (f32 operands via VGPR roundtrip) with the split epilogue.
// ---------------------------------------------------------------------------
__global__ __launch_bounds__(256)
void gemm_qkv_f32(const float* __restrict__ A, const float* __restrict__ B,
                  const float* __restrict__ bias, bf16* __restrict__ qkv2,
                  bf16* __restrict__ vt) {
  const int K = DMODEL;
  __shared__ bf16 sA[128 * 64];
  __shared__ bf16 sB[128 * 64];
  const int tid  = threadIdx.x;
  const int lane = tid & 63;
  const int wave = tid >> 6;
  const int wm = wave >> 1, wn = wave & 1;
  const int tileM = blockIdx.y * 128;
  const int tileN = blockIdx.x * 128;
  const int lrow = lane & 15;
  const int quad = lane >> 4;
  const int kq   = quad * 8;

  f32x4 acc[4][4];
#pragma unroll
  for (int i = 0; i < 4; i++)
#pragma unroll
    for (int j = 0; j < 4; j++) acc[i][j] = (f32x4){0.f, 0.f, 0.f, 0.f};

  const int r0 = tid >> 4;
  const int cc = (tid & 15) * 4;

  for (int k0 = 0; k0 < K; k0 += 64) {
    uint2 ra[8], rb[8];
#pragma unroll
    for (int i = 0; i < 8; i++) {
      int row = r0 + i * 16;
      ra[i] = pack4(*(const float4*)(A + (size_t)(tileM + row) * K + k0 + cc));
      rb[i] = pack4(*(const float4*)(B + (size_t)(tileN + row) * K + k0 + cc));
    }
    __syncthreads();
#pragma unroll
    for (int i = 0; i < 8; i++) {
      int row = r0 + i * 16;
      *(uint2*)(sA + row * 64 + cc) = ra[i];
      *(uint2*)(sB + row * 64 + cc) = rb[i];
    }
    __syncthreads();
#pragma unroll
    for (int ks = 0; ks < 2; ks++) {
      short8 afrag[4], bfrag[4];
#pragma unroll
      for (int mi = 0; mi < 4; mi++)
        afrag[mi] = *(const short8*)(sA + (wm * 64 + mi * 16 + lrow) * 64 + ks * 32 + kq);
#pragma unroll
      for (int ni = 0; ni < 4; ni++)
        bfrag[ni] = *(const short8*)(sB + (wn * 64 + ni * 16 + lrow) * 64 + ks * 32 + kq);
#pragma unroll
      for (int mi = 0; mi < 4; mi++)
#pragma unroll
        for (int ni = 0; ni < 4; ni++)
          acc[mi][ni] = __builtin_amdgcn_mfma_f32_16x16x32_bf16(afrag[mi], bfrag[ni], acc[mi][ni], 0, 0, 0);
    }
  }
#pragma unroll
  for (int ni = 0; ni < 4; ni++) {
    int col = tileN + wn * 64 + ni * 16 + lrow;
    float bv = bias[col];
    if (col < 2 * DMODEL) {
      float sc = (col < DMODEL) ? QSCALE : 1.0f;
#pragma unroll
      for (int mi = 0; mi < 4; mi++) {
        int row0 = tileM + wm * 64 + mi * 16 + quad * 4;
#pragma unroll
        for (int r = 0; r < 4; r++)
          qkv2[(size_t)(row0 + r) * 2048 + col] = (bf16)((acc[mi][ni][r] + bv) * sc);
      }
    } else {
      int c2 = col - 2 * DMODEL;
      int hh = c2 >> 6, dd = c2 & 63;
      bf16* vrow = vt + ((size_t)(hh * 64 + dd)) * S_LEN;
#pragma unroll
      for (int mi = 0; mi < 4; mi++) {
        int row0 = tileM + wm * 64 + mi * 16 + quad * 4;
        float4 v = {acc[mi][ni][0] + bv, acc[mi][ni][1] + bv,
                    acc[mi][ni][2] + bv, acc[mi][ni][3] + bv};
        *(uint2*)(vrow + row0) = pack4(v);
      }
    }
  }
}

// Fallback O-proj (A bf16, B f32), 128x128 tiles.
__global__ __launch_bounds__(256)
void gemm_oproj_f32w(const bf16* __restrict__ A, const float* __restrict__ B,
                     const float* __restrict__ bias, float* __restrict__ C) {
  const int K = DMODEL, N = DMODEL;
  __shared__ bf16 sA[128 * 64];
  __shared__ bf16 sB[128 * 64];
  const int tid  = threadIdx.x;
  const int lane = tid & 63;
  const int wave = tid >> 6;
  const int wm = wave >> 1, wn = wave & 1;
  const int tileM = blockIdx.y * 128;
  const int tileN = blockIdx.x * 128;
  const int lrow = lane & 15;
  const int quad = lane >> 4;
  const int kq   = quad * 8;

  f32x4 acc[4][4];
#pragma unroll
  for (int i = 0; i < 4; i++)
#pragma unroll
    for (int j = 0; j < 4; j++) acc[i][j] = (f32x4){0.f, 0.f, 0.f, 0.f};

  const int a_r0 = tid >> 3;
  const int a_cc = (tid & 7) * 8;
  const int b_r0 = tid >> 4;
  const int b_cc = (tid & 15) * 4;

  for (int k0 = 0; k0 < K; k0 += 64) {
    uint4 ra[4];
    uint2 rb[8];
#pragma unroll
    for (int i = 0; i < 4; i++)
      ra[i] = *(const uint4*)(A + (size_t)(tileM + a_r0 + i * 32) * K + k0 + a_cc);
#pragma unroll
    for (int i = 0; i < 8; i++)
      rb[i] = pack4(*(const float4*)(B + (size_t)(tileN + b_r0 + i * 16) * K + k0 + b_cc));
    __syncthreads();
#pragma unroll
    for (int i = 0; i < 4; i++)
      *(uint4*)(sA + (a_r0 + i * 32) * 64 + a_cc) = ra[i];
#pragma unroll
    for (int i = 0; i < 8; i++)
      *(uint2*)(sB + (b_r0 + i * 16) * 64 + b_cc) = rb[i];
    __syncthreads();
#pragma unroll
    for (int ks = 0; ks < 2; ks++) {
      short8 afrag[4], bfrag[4];
#pragma unroll
      for (int mi = 0; mi < 4; mi++)
        afrag[mi] = *(const short8*)(sA + (wm * 64 + mi * 16 + lrow) * 64 + ks * 32 + kq);
#pragma unroll
      for (int ni = 0; ni < 4; ni++)
        bfrag[ni] = *(const short8*)(sB + (wn * 64 + ni * 16 + lrow) * 64 + ks * 32 + kq);
#pragma unroll
      for (int mi = 0; mi < 4; mi++)
#pragma unroll
        for (int ni = 0; ni < 4; ni++)
          acc[mi][ni] = __builtin_amdgcn_mfma_f32_16x16x32_bf16(afrag[mi], bfrag[ni], acc[mi][ni], 0, 0, 0);
    }
  }
#pragma unroll
  for (int ni = 0; ni < 4; ni++) {
    int col = tileN + wn * 64 + ni * 16 + lrow;
    float bv = bias[col];
#pragma unroll
    for (int mi = 0; mi < 4; mi++) {
      int row0 = tileM + wm * 64 + mi * 16 + quad * 4;
#pragma unroll
      for (int r = 0; r < 4; r++)
        C[(size_t)(row0 + r) * N + col] = acc[mi][ni][r] + bv;
    }
  }
}

// ---------------------------------------------------------------------------
// Flash attention v12: fixes v11's makespan imbalance (23.7% occupancy from
// unequal causal block lengths on an exactly-fitting grid).
//  - QBLK=32: each block owns 32 q-rows; 4 waves = (p = 64-key sub-tile,
//    kh = 32-key half) cover a 128-key step. Per-wave quadrant math (swapped
//    QK^T, in-reg softmax, permlane32_swap, 32x32x16 MFMA) is v11's verbatim.
//  - PAIRED ASSIGNMENTS: block processes q-tile idx then 127-idx; iteration
//    count ~34 UNIFORM across all 1024 blocks -> 4 resident blocks/CU stay
//    busy to the end (no long-block tail).
//  - 128-key K-steps halve barriers and DMA-issue overhead per key.
//  - LDS 33KB (A=K-tile 16KB, B=V^T-tile 16KB as two 64x64 rot sub-tiles)
//    -> 4 blocks/CU; VGPR ~60 under launch_bounds(256,4)'s 128 cap.
//  - Epilogue: 4-way O/l combine via dead LDS; wave0 normalizes and stores.
// ---------------------------------------------------------------------------
__global__ __launch_bounds__(256, 4)
void attn_kernel(const bf16* __restrict__ qkv2, const bf16* __restrict__ vt,
                 bf16* __restrict__ attn_out, const int* __restrict__ causal_ptr) {
  __shared__ bf16 smem[2][128 * 64];  // [0]=K tile (2 rot sub-tiles), [1]=V^T tile
  __shared__ float lbuf[128];

  const int tid  = threadIdx.x;
  const int lane = tid & 63;
  const int wave = tid >> 6;
  const int p    = wave >> 1;         // 64-key sub-tile index
  const int kh   = wave & 1;          // 32-key half within sub-tile

  // XCD head-clustering: id&7 = XCD -> head pair {x, x+8} per XCD (K/V ~2MB in L2)
  const int id  = blockIdx.y * 64 + blockIdx.x;   // 0..1023
  const int xcd = id & 7;
  const int hh  = (id >> 3) & 1;
  const int idx = id >> 4;            // 0..63
  const int h   = xcd + (hh << 3);
  const bool causal = (*causal_ptr) != 0;

  const int l31 = lane & 31;
  const int hi  = lane >> 5;
  const int trl = lane >> 3;                          // 0..7
  const int cgl = (((lane & 7) - trl) & 7) << 3;      // rotated col, mult of 8

  const bf16* Qb = qkv2 + h * HD;                     // [S][2048]
  const bf16* Kb = qkv2 + DMODEL + h * HD;
  const bf16* Vb = vt + (size_t)(h * HD) * S_LEN;     // [64][S]

  bf16* const A  = smem[0];
  bf16* const B0 = smem[1];
  bf16* const B1 = smem[1] + 4096;
  const bf16* const Ap = smem[0] + p * 4096;
  const bf16* const Bp = smem[1] + p * 4096;

  // per-wave staging bases (row = ch*8+trl; K: ch=wave*4+i, V: ch=wave*2+i)
  const bf16* const kB = Kb + (size_t)(wave * 32 + trl) * 2048 + cgl;
  const bf16* const vB = Vb + (size_t)(wave * 16 + trl) * S_LEN + cgl;

  for (int a = 0; a < 2; a++) {
    const int qi    = a ? (127 - idx) : idx;
    const int qbase = qi * 32;
    const int q_g   = qbase + l31;       // this lane's q-row
    const int wrmax = qbase + 31;
    const int niter = causal ? ((qi >> 2) + 1) : 32;

    __syncthreads();   // a=1: prior epilogue's smem reads done before restaging

    // ---- prologue: K[0] -> A, V[0] -> B0|B1; Q straight to registers ----
#pragma unroll
    for (int i = 0; i < 4; i++)
      gload_lds16(kB + (size_t)i * 8 * 2048, A + (wave * 4 + i) * 512);
#pragma unroll
    for (int i = 0; i < 2; i++) {
      gload_lds16(vB + (size_t)i * 8 * S_LEN,      B0 + (wave * 2 + i) * 512);
      gload_lds16(vB + (size_t)i * 8 * S_LEN + 64, B1 + (wave * 2 + i) * 512);
    }
    short8 qf[4];
#pragma unroll
    for (int kd = 0; kd < 4; kd++)
      qf[kd] = *(const short8*)(Qb + (size_t)q_g * 2048 + kd * 16 + hi * 8);

    f32x16 oacc[2];
#pragma unroll
    for (int nc = 0; nc < 2; nc++)
#pragma unroll
      for (int e = 0; e < 16; e++) oacc[nc][e] = 0.f;
    float l_st = 0.f;

    const bf16* kP = kB + (size_t)128 * 2048;   // next K tile base
    const bf16* vP = vB + 128;                  // next V tile base

    __syncthreads();   // prologue DMA drained

    for (int jt = 0; jt < niter; jt++) {
      const int kh32 = jt * 128 + p * 64 + kh * 32;   // wave's key base
      const bool live = !(causal && kh32 > wrmax);    // wave-uniform

      uint32_t pw[2][4];  // PV A-frag words: [16-k chunk within half][word]
      if (live) {
        // ---- S^T = K Q^T for this wave's 32x32 quadrant (K from A_p) ----
        f32x16 sacc;
#pragma unroll
        for (int e = 0; e < 16; e++) sacc[e] = 0.f;
        __builtin_amdgcn_s_setprio(1);
#pragma unroll
        for (int kd = 0; kd < 4; kd++) {
          short8 kf = *(const short8*)(Ap + rot_idx(kh * 32 + l31, kd * 16 + hi * 8));
          sacc = __builtin_amdgcn_mfma_f32_32x32x16_bf16(kf, qf[kd], sacc, 0, 0, 0);
        }
        __builtin_amdgcn_s_setprio(0);
        // lane holds S[q = q_g][k = kh32 + 8g + 4hi + r]; fused
        // exp2 -> causal mask -> psum -> bf16 pair-pack.
        const bool nm = causal && (kh32 + 31 > qbase);
        uint32_t pku[4][2];
        float psum = 0.f;
#pragma unroll
        for (int g = 0; g < 4; g++) {
#pragma unroll
          for (int h2 = 0; h2 < 2; h2++) {
            float v0 = __builtin_amdgcn_exp2f(sacc[g * 4 + h2 * 2]);
            float v1 = __builtin_amdgcn_exp2f(sacc[g * 4 + h2 * 2 + 1]);
            if (nm) {
              int kg = kh32 + g * 8 + hi * 4 + h2 * 2;
              if (kg > q_g)     v0 = 0.f;
              if (kg + 1 > q_g) v1 = 0.f;
            }
            psum += v0 + v1;
            pku[g][h2] = pack2(v0, v1);
          }
        }
        l_st += psum;
        // permlane32_swap builds the 32x32x16 A-fragment on the VALU.
#pragma unroll
        for (int c2 = 0; c2 < 2; c2++) {
#pragma unroll
          for (int h2 = 0; h2 < 2; h2++) {
            uint2u sw = __builtin_amdgcn_permlane32_swap(
                pku[2 * c2][h2], pku[2 * c2 + 1][h2], false, false);
            pw[c2][h2]     = sw[0];
            pw[c2][2 + h2] = sw[1];
          }
        }
      }

      __syncthreads();  // all waves done reading A; V[jt] was drained earlier

      if (jt + 1 < niter) {  // refill A with K[jt+1] while PV reads B
#pragma unroll
        for (int i = 0; i < 4; i++)
          gload_lds16(kP + (size_t)i * 8 * 2048, A + (wave * 4 + i) * 512);
        kP += (size_t)128 * 2048;
      }

      if (live) {
        // ---- O += P V over this wave's 32-key quadrant (V from B_p) ----
        __builtin_amdgcn_s_setprio(1);
#pragma unroll
        for (int c2 = 0; c2 < 2; c2++) {
          if (causal && (kh32 + c2 * 16 > wrmax)) continue;  // masked chunk
          union { short8 s; uint32_t u[4]; } pf;
#pragma unroll
          for (int w = 0; w < 4; w++) pf.u[w] = pw[c2][w];
#pragma unroll
          for (int nc = 0; nc < 2; nc++) {
            short8 vf = *(const short8*)(Bp +
                rot_idx(nc * 32 + l31, (kh * 2 + c2) * 16 + hi * 8));
            oacc[nc] = __builtin_amdgcn_mfma_f32_32x32x16_bf16(pf.s, vf, oacc[nc], 0, 0, 0);
          }
        }
        __builtin_amdgcn_s_setprio(0);
      }

      __syncthreads();  // all waves done reading B; K[jt+1] DMA drained

      if (jt + 1 < niter) {  // refill B with V[jt+1]; drains at next barrier
#pragma unroll
        for (int i = 0; i < 2; i++) {
          gload_lds16(vP + (size_t)i * 8 * S_LEN,      B0 + (wave * 2 + i) * 512);
          gload_lds16(vP + (size_t)i * 8 * S_LEN + 64, B1 + (wave * 2 + i) * 512);
        }
        vP += 128;
      }
    }  // jt

    // ---- epilogue: 4-way O/l combine (all waves share the same 32 q-rows);
    // wave 0 normalizes and stores.
    float ltot = l_st + __shfl_xor(l_st, 32);   // sum over hi (disjoint keys)
    float* obuf = (float*)smem;                 // 24KB of the 32KB reused
    if (wave != 0) {
      float* ob = obuf + (wave - 1) * 2048;
#pragma unroll
      for (int nc = 0; nc < 2; nc++)
#pragma unroll
        for (int e = 0; e < 16; e++)
          ob[(nc * 16 + e) * 64 + lane] = oacc[nc][e];
      if (hi == 0) lbuf[wave * 32 + l31] = ltot;
    }
    __syncthreads();
    if (wave == 0) {
#pragma unroll
      for (int w = 0; w < 3; w++) {
        float* ob = obuf + w * 2048;
#pragma unroll
        for (int nc = 0; nc < 2; nc++)
#pragma unroll
          for (int e = 0; e < 16; e++)
            oacc[nc][e] += ob[(nc * 16 + e) * 64 + lane];
      }
      ltot += lbuf[32 + l31] + lbuf[64 + l31] + lbuf[96 + l31];
      if (hi == 0) lbuf[l31] = ltot;   // DS ops are in-order per wave
      float invl[4][4];
#pragma unroll
      for (int g = 0; g < 4; g++) {
        f32x4 lv = *(const f32x4*)(lbuf + g * 8 + hi * 4);
#pragma unroll
        for (int r = 0; r < 4; r++) invl[g][r] = 1.0f / fmaxf(lv[r], 1e-30f);
      }
#pragma unroll
      for (int nc = 0; nc < 2; nc++) {
#pragma unroll
        for (int g = 0; g < 4; g++) {
#pragma unroll
          for (int r = 0; r < 4; r++) {
            int qg = qbase + g * 8 + hi * 4 + r;
            int col = h * HD + nc * 32 + l31;
            attn_out[(size_t)qg * DMODEL + col] = (bf16)(oacc[nc][g * 4 + r] * invl[g][r]);
          }
        }
      }
    }
  }  // a
}

// ---------------------------------------------------------------------------
extern "C" void kernel_launch(void* const* d_in, const int* in_sizes, int n_in,
                              void* d_out, int out_size, void* d_ws, size_t ws_size,
                              hipStream_t stream) {
  const float* x     = (const float*)d_in[0];
  const float* w_qkv = (const float*)d_in[1];
  const float* b_qkv = (const float*)d_in[2];
  const float* w_o   = (const float*)d_in[3];
  const float* b_o   = (const float*)d_in[4];
  const int*   cm    = (const int*)d_in[5];

  char* ws = (char*)d_ws;
  bf16* qkv2 = (bf16*)ws;                         // [4096][2048] Q|K (Q pre-scaled)
  bf16* vt   = (bf16*)(ws + 16777216);            // [16][64][4096] V^T per head
  bf16* attn = (bf16*)(ws + 25165824);            // [4096][1024]
  bf16* xb   = (bf16*)(ws + 33554432);            // [4096][1024]
  bf16* wqb  = (bf16*)(ws + 41943040);            // [3072][1024]
  bf16* wob  = (bf16*)(ws + 48234496);            // [1024][1024] (end 50331648)

  dim3 blk(256);
  const bool fast = (ws_size >= (size_t)50331648);

  if (fast) {
    const int ntot = S_LEN * DMODEL + 3 * DMODEL * DMODEL + DMODEL * DMODEL;
    cvt_all<<<dim3((ntot / 4 + 255) / 256), blk, 0, stream>>>(
        x, w_qkv, w_o, xb, wqb, wob);
    gemm_qkv<<<dim3(3 * DMODEL / 128, S_LEN / 128), blk, 0, stream>>>(
        xb, wqb, b_qkv, qkv2, vt);
    attn_kernel<<<dim3(64, NH), blk, 0, stream>>>(qkv2, vt, attn, cm);
    gemm_oproj<<<dim3(DMODEL / 64, S_LEN / 128), blk, 0, stream>>>(
        attn, wob, b_o, (float*)d_out);
  } else {
    gemm_qkv_f32<<<dim3(3 * DMODEL / 128, S_LEN / 128), blk, 0, stream>>>(
        x, w_qkv, b_qkv, qkv2, vt);
    attn_kernel<<<dim3(64, NH), blk, 0, stream>>>(qkv2, vt, attn, cm);
    gemm_oproj_f32w<<<dim3(DMODEL / 128, S_LEN / 128), blk, 0, stream>>>(
        attn, w_o, b_o, (float*)d_out);
  }
}

// Round 9
// 205.153 us; speedup vs baseline: 1.1350x; 1.1350x over previous
//
#include <hip/hip_runtime.h>
#include <hip/hip_bf16.h>
#include <stdint.h>

typedef __attribute__((ext_vector_type(8))) short short8;
typedef __attribute__((ext_vector_type(4))) float f32x4;
typedef __attribute__((ext_vector_type(16))) float f32x16;
typedef __attribute__((ext_vector_type(2))) unsigned int uint2u;
typedef __hip_bfloat16 bf16;

#define S_LEN 4096
#define DMODEL 1024
#define NH 16
#define HD 64
// Q pre-scale: 1/sqrt(64) * log2(e)  -> softmax via raw v_exp_f32 (2^x)
#define QSCALE 0.1803368801111f

static __device__ inline uint2 pack4(float4 v) {
  union { uint2 u; bf16 h[4]; } p;
  p.h[0] = (bf16)v.x; p.h[1] = (bf16)v.y; p.h[2] = (bf16)v.z; p.h[3] = (bf16)v.w;
  return p.u;
}

static __device__ inline uint32_t pack2(float a, float b) {
  union { uint32_t u; bf16 h[2]; } p;
  p.h[0] = (bf16)a; p.h[1] = (bf16)b;
  return p.u;
}

static __device__ inline float b2f(short s) {
  union { short s; bf16 h; } u; u.s = s; return (float)u.h;
}

// async global->LDS, 16B per lane. Global address is PER-LANE (gather);
// LDS dest = wave-uniform base + lane*16.
static __device__ inline void gload_lds16(const bf16* g, bf16* l) {
  __builtin_amdgcn_global_load_lds(
      (const __attribute__((address_space(1))) unsigned int*)g,
      (__attribute__((address_space(3))) unsigned int*)l, 16, 0, 0);
}

// Rotation layout for 64-wide LDS tiles (row stride 64, no padding): element
// (r,c) lives at r*64 + ((c + 8*(r&7)) & 63). DMA staging lanes fetch a
// rotated global column so async writes land in this layout for free; b128
// fragment reads stay 16B-contiguous and spread bank groups evenly.
static __device__ inline int rot_idx(int r, int c) {
  return r * 64 + ((c + ((r & 7) << 3)) & 63);
}

// ---------------------------------------------------------------------------
// One segmented f32->bf16 conversion kernel for x, w_qkv, w_o.
// ---------------------------------------------------------------------------
__global__ __launch_bounds__(256)
void cvt_all(const float* __restrict__ x, const float* __restrict__ wq,
             const float* __restrict__ wo, bf16* __restrict__ xb,
             bf16* __restrict__ wqb, bf16* __restrict__ wob) {
  const int nx = S_LEN * DMODEL;
  const int nq = 3 * DMODEL * DMODEL;
  const int no = DMODEL * DMODEL;
  int i = (blockIdx.x * 256 + threadIdx.x) * 4;
  if (i < nx) {
    *(uint2*)(xb + i) = pack4(*(const float4*)(x + i));
  } else if (i < nx + nq) {
    int j = i - nx;
    *(uint2*)(wqb + j) = pack4(*(const float4*)(wq + j));
  } else if (i < nx + nq + no) {
    int j = i - nx - nq;
    *(uint2*)(wob + j) = pack4(*(const float4*)(wo + j));
  }
}

// ---------------------------------------------------------------------------
// QKV GEMM (bf16 ops, global_load_lds staging, ROTATION LAYOUT -> conflict-
// free ds_read_b128). Epilogue splits output:
//   cols [0,2048): qkv2[row][col]   (Q cols scaled by QSCALE)
//   cols [2048,3072): V written TRANSPOSED per head: vt[h][d][row]
// ---------------------------------------------------------------------------
__global__ __launch_bounds__(256)
void gemm_qkv(const bf16* __restrict__ A, const bf16* __restrict__ B,
              const float* __restrict__ bias, bf16* __restrict__ qkv2,
              bf16* __restrict__ vt) {
  const int K = DMODEL;
  __shared__ bf16 sA[128 * 64];
  __shared__ bf16 sB[128 * 64];
  const int tid  = threadIdx.x;
  const int lane = tid & 63;
  const int wave = tid >> 6;
  const int wm = wave >> 1, wn = wave & 1;
  const int tileM = blockIdx.y * 128;
  const int tileN = blockIdx.x * 128;

  const int lrow = lane & 15;
  const int quad = lane >> 4;
  const int kq   = quad * 8;

  f32x4 acc[4][4];
#pragma unroll
  for (int i = 0; i < 4; i++)
#pragma unroll
    for (int j = 0; j < 4; j++) acc[i][j] = (f32x4){0.f, 0.f, 0.f, 0.f};

  // staging lane geometry: row-in-chunk + rotated global column
  const int trl = lane >> 3;                          // 0..7
  const int cgl = (((lane & 7) - trl) & 7) << 3;      // rotated col, mult of 8
  const bf16* aP[4];
  const bf16* bP[4];
#pragma unroll
  for (int c = 0; c < 4; c++) {
    int ch = wave * 4 + c;
    aP[c] = A + (size_t)(tileM + ch * 8 + trl) * K + cgl;
    bP[c] = B + (size_t)(tileN + ch * 8 + trl) * K + cgl;
  }

  for (int k0 = 0; k0 < K; k0 += 64) {
    __syncthreads();
#pragma unroll
    for (int c = 0; c < 4; c++) {
      int ch = wave * 4 + c;
      gload_lds16(aP[c] + k0, sA + ch * 512);
      gload_lds16(bP[c] + k0, sB + ch * 512);
    }
    __syncthreads();
#pragma unroll
    for (int ks = 0; ks < 2; ks++) {
      short8 afrag[4], bfrag[4];
#pragma unroll
      for (int mi = 0; mi < 4; mi++)
        afrag[mi] = *(const short8*)(sA + rot_idx(wm * 64 + mi * 16 + lrow, ks * 32 + kq));
#pragma unroll
      for (int ni = 0; ni < 4; ni++)
        bfrag[ni] = *(const short8*)(sB + rot_idx(wn * 64 + ni * 16 + lrow, ks * 32 + kq));
#pragma unroll
      for (int mi = 0; mi < 4; mi++)
#pragma unroll
        for (int ni = 0; ni < 4; ni++)
          acc[mi][ni] = __builtin_amdgcn_mfma_f32_16x16x32_bf16(afrag[mi], bfrag[ni], acc[mi][ni], 0, 0, 0);
    }
  }

#pragma unroll
  for (int ni = 0; ni < 4; ni++) {
    int col = tileN + wn * 64 + ni * 16 + lrow;
    float bv = bias[col];
    if (col < 2 * DMODEL) {
      float sc = (col < DMODEL) ? QSCALE : 1.0f;
#pragma unroll
      for (int mi = 0; mi < 4; mi++) {
        int row0 = tileM + wm * 64 + mi * 16 + quad * 4;
#pragma unroll
        for (int r = 0; r < 4; r++)
          qkv2[(size_t)(row0 + r) * 2048 + col] = (bf16)((acc[mi][ni][r] + bv) * sc);
      }
    } else {
      int cc = col - 2 * DMODEL;
      int hh = cc >> 6, dd = cc & 63;
      bf16* vrow = vt + ((size_t)(hh * 64 + dd)) * S_LEN;
#pragma unroll
      for (int mi = 0; mi < 4; mi++) {
        int row0 = tileM + wm * 64 + mi * 16 + quad * 4;
        float4 v = {acc[mi][ni][0] + bv, acc[mi][ni][1] + bv,
                    acc[mi][ni][2] + bv, acc[mi][ni][3] + bv};
        *(uint2*)(vrow + row0) = pack4(v);
      }
    }
  }
}

// ---------------------------------------------------------------------------
// O-projection GEMM (bf16 ops -> f32 out), 128x64 tiles, rotation layout.
// ---------------------------------------------------------------------------
__global__ __launch_bounds__(256)
void gemm_oproj(const bf16* __restrict__ A, const bf16* __restrict__ B,
                const float* __restrict__ bias, float* __restrict__ C) {
  const int K = DMODEL, N = DMODEL;
  __shared__ bf16 sA[128 * 64];
  __shared__ bf16 sB[64 * 64];
  const int tid  = threadIdx.x;
  const int lane = tid & 63;
  const int wave = tid >> 6;
  const int wm = wave >> 1, wn = wave & 1;     // wave tile: 64 rows x 32 cols
  const int tileM = blockIdx.y * 128;          // gridDim.y = 32
  const int tileN = blockIdx.x * 64;           // gridDim.x = 16

  const int lrow = lane & 15;
  const int quad = lane >> 4;
  const int kq   = quad * 8;

  f32x4 acc[4][2];
#pragma unroll
  for (int i = 0; i < 4; i++)
#pragma unroll
    for (int j = 0; j < 2; j++) acc[i][j] = (f32x4){0.f, 0.f, 0.f, 0.f};

  const int trl = lane >> 3;
  const int cgl = (((lane & 7) - trl) & 7) << 3;
  const bf16* aP[4];
  const bf16* bP[2];
#pragma unroll
  for (int c = 0; c < 4; c++) {
    int ch = wave * 4 + c;
    aP[c] = A + (size_t)(tileM + ch * 8 + trl) * K + cgl;
  }
#pragma unroll
  for (int c = 0; c < 2; c++) {
    int ch = wave * 2 + c;
    bP[c] = B + (size_t)(tileN + ch * 8 + trl) * K + cgl;
  }

  for (int k0 = 0; k0 < K; k0 += 64) {
    __syncthreads();
#pragma unroll
    for (int c = 0; c < 4; c++)
      gload_lds16(aP[c] + k0, sA + (wave * 4 + c) * 512);
#pragma unroll
    for (int c = 0; c < 2; c++)
      gload_lds16(bP[c] + k0, sB + (wave * 2 + c) * 512);
    __syncthreads();
#pragma unroll
    for (int ks = 0; ks < 2; ks++) {
      short8 afrag[4], bfrag[2];
#pragma unroll
      for (int mi = 0; mi < 4; mi++)
        afrag[mi] = *(const short8*)(sA + rot_idx(wm * 64 + mi * 16 + lrow, ks * 32 + kq));
#pragma unroll
      for (int ni = 0; ni < 2; ni++)
        bfrag[ni] = *(const short8*)(sB + rot_idx(wn * 32 + ni * 16 + lrow, ks * 32 + kq));
#pragma unroll
      for (int mi = 0; mi < 4; mi++)
#pragma unroll
        for (int ni = 0; ni < 2; ni++)
          acc[mi][ni] = __builtin_amdgcn_mfma_f32_16x16x32_bf16(afrag[mi], bfrag[ni], acc[mi][ni], 0, 0, 0);
    }
  }

#pragma unroll
  for (int ni = 0; ni < 2; ni++) {
    int col = tileN + wn * 32 + ni * 16 + lrow;
    float bv = bias[col];
#pragma unroll
    for (int mi = 0; mi < 4; mi++) {
      int row0 = tileM + wm * 64 + mi * 16 + quad * 4;
#pragma unroll
      for (int r = 0; r < 4; r++)
        C[(size_t)(row0 + r) * N + col] = acc[mi][ni][r] + bv;
    }
  }
}

// ---------------------------------------------------------------------------
// Fallback QKV GEMM (f32 operands via VGPR roundtrip) with the split epilogue.
// ---------------------------------------------------------------------------
__global__ __launch_bounds__(256)
void gemm_qkv_f32(const float* __restrict__ A, const float* __restrict__ B,
                  const float* __restrict__ bias, bf16* __restrict__ qkv2,
                  bf16* __restrict__ vt) {
  const int K = DMODEL;
  __shared__ bf16 sA[128 * 64];
  __shared__ bf16 sB[128 * 64];
  const int tid  = threadIdx.x;
  const int lane = tid & 63;
  const int wave = tid >> 6;
  const int wm = wave >> 1, wn = wave & 1;
  const int tileM = blockIdx.y * 128;
  const int tileN = blockIdx.x * 128;
  const int lrow = lane & 15;
  const int quad = lane >> 4;
  const int kq   = quad * 8;

  f32x4 acc[4][4];
#pragma unroll
  for (int i = 0; i < 4; i++)
#pragma unroll
    for (int j = 0; j < 4; j++) acc[i][j] = (f32x4){0.f, 0.f, 0.f, 0.f};

  const int r0 = tid >> 4;
  const int cc = (tid & 15) * 4;

  for (int k0 = 0; k0 < K; k0 += 64) {
    uint2 ra[8], rb[8];
#pragma unroll
    for (int i = 0; i < 8; i++) {
      int row = r0 + i * 16;
      ra[i] = pack4(*(const float4*)(A + (size_t)(tileM + row) * K + k0 + cc));
      rb[i] = pack4(*(const float4*)(B + (size_t)(tileN + row) * K + k0 + cc));
    }
    __syncthreads();
#pragma unroll
    for (int i = 0; i < 8; i++) {
      int row = r0 + i * 16;
      *(uint2*)(sA + row * 64 + cc) = ra[i];
      *(uint2*)(sB + row * 64 + cc) = rb[i];
    }
    __syncthreads();
#pragma unroll
    for (int ks = 0; ks < 2; ks++) {
      short8 afrag[4], bfrag[4];
#pragma unroll
      for (int mi = 0; mi < 4; mi++)
        afrag[mi] = *(const short8*)(sA + (wm * 64 + mi * 16 + lrow) * 64 + ks * 32 + kq);
#pragma unroll
      for (int ni = 0; ni < 4; ni++)
        bfrag[ni] = *(const short8*)(sB + (wn * 64 + ni * 16 + lrow) * 64 + ks * 32 + kq);
#pragma unroll
      for (int mi = 0; mi < 4; mi++)
#pragma unroll
        for (int ni = 0; ni < 4; ni++)
          acc[mi][ni] = __builtin_amdgcn_mfma_f32_16x16x32_bf16(afrag[mi], bfrag[ni], acc[mi][ni], 0, 0, 0);
    }
  }
#pragma unroll
  for (int ni = 0; ni < 4; ni++) {
    int col = tileN + wn * 64 + ni * 16 + lrow;
    float bv = bias[col];
    if (col < 2 * DMODEL) {
      float sc = (col < DMODEL) ? QSCALE : 1.0f;
#pragma unroll
      for (int mi = 0; mi < 4; mi++) {
        int row0 = tileM + wm * 64 + mi * 16 + quad * 4;
#pragma unroll
        for (int r = 0; r < 4; r++)
          qkv2[(size_t)(row0 + r) * 2048 + col] = (bf16)((acc[mi][ni][r] + bv) * sc);
      }
    } else {
      int c2 = col - 2 * DMODEL;
      int hh = c2 >> 6, dd = c2 & 63;
      bf16* vrow = vt + ((size_t)(hh * 64 + dd)) * S_LEN;
#pragma unroll
      for (int mi = 0; mi < 4; mi++) {
        int row0 = tileM + wm * 64 + mi * 16 + quad * 4;
        float4 v = {acc[mi][ni][0] + bv, acc[mi][ni][1] + bv,
                    acc[mi][ni][2] + bv, acc[mi][ni][3] + bv};
        *(uint2*)(vrow + row0) = pack4(v);
      }
    }
  }
}

// Fallback O-proj (A bf16, B f32), 128x128 tiles.
__global__ __launch_bounds__(256)
void gemm_oproj_f32w(const bf16* __restrict__ A, const float* __restrict__ B,
                     const float* __restrict__ bias, float* __restrict__ C) {
  const int K = DMODEL, N = DMODEL;
  __shared__ bf16 sA[128 * 64];
  __shared__ bf16 sB[128 * 64];
  const int tid  = threadIdx.x;
  const int lane = tid & 63;
  const int wave = tid >> 6;
  const int wm = wave >> 1, wn = wave & 1;
  const int tileM = blockIdx.y * 128;
  const int tileN = blockIdx.x * 128;
  const int lrow = lane & 15;
  const int quad = lane >> 4;
  const int kq   = quad * 8;

  f32x4 acc[4][4];
#pragma unroll
  for (int i = 0; i < 4; i++)
#pragma unroll
    for (int j = 0; j < 4; j++) acc[i][j] = (f32x4){0.f, 0.f, 0.f, 0.f};

  const int a_r0 = tid >> 3;
  const int a_cc = (tid & 7) * 8;
  const int b_r0 = tid >> 4;
  const int b_cc = (tid & 15) * 4;

  for (int k0 = 0; k0 < K; k0 += 64) {
    uint4 ra[4];
    uint2 rb[8];
#pragma unroll
    for (int i = 0; i < 4; i++)
      ra[i] = *(const uint4*)(A + (size_t)(tileM + a_r0 + i * 32) * K + k0 + a_cc);
#pragma unroll
    for (int i = 0; i < 8; i++)
      rb[i] = pack4(*(const float4*)(B + (size_t)(tileN + b_r0 + i * 16) * K + k0 + b_cc));
    __syncthreads();
#pragma unroll
    for (int i = 0; i < 4; i++)
      *(uint4*)(sA + (a_r0 + i * 32) * 64 + a_cc) = ra[i];
#pragma unroll
    for (int i = 0; i < 8; i++)
      *(uint2*)(sB + (b_r0 + i * 16) * 64 + b_cc) = rb[i];
    __syncthreads();
#pragma unroll
    for (int ks = 0; ks < 2; ks++) {
      short8 afrag[4], bfrag[4];
#pragma unroll
      for (int mi = 0; mi < 4; mi++)
        afrag[mi] = *(const short8*)(sA + (wm * 64 + mi * 16 + lrow) * 64 + ks * 32 + kq);
#pragma unroll
      for (int ni = 0; ni < 4; ni++)
        bfrag[ni] = *(const short8*)(sB + (wn * 64 + ni * 16 + lrow) * 64 + ks * 32 + kq);
#pragma unroll
      for (int mi = 0; mi < 4; mi++)
#pragma unroll
        for (int ni = 0; ni < 4; ni++)
          acc[mi][ni] = __builtin_amdgcn_mfma_f32_16x16x32_bf16(afrag[mi], bfrag[ni], acc[mi][ni], 0, 0, 0);
    }
  }
#pragma unroll
  for (int ni = 0; ni < 4; ni++) {
    int col = tileN + wn * 64 + ni * 16 + lrow;
    float bv = bias[col];
#pragma unroll
    for (int mi = 0; mi < 4; mi++) {
      int row0 = tileM + wm * 64 + mi * 16 + quad * 4;
#pragma unroll
      for (int r = 0; r < 4; r++)
        C[(size_t)(row0 + r) * N + col] = acc[mi][ni][r] + bv;
    }
  }
}

// ---------------------------------------------------------------------------
// Flash attention v16: chunked compute (v13's verbatim hot loop: key-range
// split x2, grid 2048, longest-first, 8 blocks/CU), but the cross-chunk
// merge is moved ACROSS A KERNEL BOUNDARY -- the only inter-block ordering /
// coherence mechanism this pipeline already provably relies on. v13/14/15's
// intra-kernel rendezvous failed three datapath variants with an invariant
// ~0.03 error (and a 468-magnitude unnormalized leak on some runs) -> the
// live handshake is the suspect; it is now gone entirely.
//   - Each chunk block dumps its kh-combined partial O as bf16 [64][64]
//     into dead d_out (ck0 -> first 8MB, ck1 -> second 8MB; W_O untouched),
//     and per-row l (f32) into the first 4 rows of its own output tile in
//     the attn buffer (disjoint writers; merge re-reads then overwrites).
//   - attn_merge (1024 blocks) normalizes: attn = (O0+O2)/(l0+l1).
// bf16 partial precision: 2^-9 relative THROUGH the divide -> ~1e-3 in
// attn, ~6e-4 in final output. No atomics, no spin, no memset.
// ---------------------------------------------------------------------------
__global__ __launch_bounds__(256, 4)
void attn_kernel(const bf16* __restrict__ qkv2, const bf16* __restrict__ vt,
                 bf16* __restrict__ attn_out, const int* __restrict__ causal_ptr,
                 bf16* __restrict__ p0, bf16* __restrict__ p1) {
  __shared__ bf16 smem[2][64 * 64];   // A=smem[0] (K tiles), B=smem[1] (V^T tiles)
  __shared__ float lbuf[64];          // kh=1 partial l

  const int tid  = threadIdx.x;
  const int lane = tid & 63;
  const int wave = tid >> 6;
  const int qh   = wave >> 1;         // q half (32 rows)
  const int kh   = wave & 1;          // key half within each 64-key tile

  // XCD head-clustered map; rank ascending => qi descending (longest first)
  const int id   = blockIdx.y * 128 + blockIdx.x;   // grid (128,16) -> 0..2047
  const int xcd  = id & 7;
  const int hh   = (id >> 3) & 1;
  const int h    = xcd + (hh << 3);
  const int ck   = (id >> 4) & 1;     // key chunk
  const int rank = id >> 5;           // 0..63
  const int qi   = 63 - rank;
  const int qbase = qi * 64;
  const bool causal = (*causal_ptr) != 0;

  const int l31 = lane & 31;
  const int hi  = lane >> 5;
  const int trl = lane >> 3;                          // 0..7
  const int cgl = (((lane & 7) - trl) & 7) << 3;      // rotated col, mult of 8

  const bf16* Qb = qkv2 + h * HD;                     // [S][2048]
  const bf16* Kb = qkv2 + DMODEL + h * HD;
  const bf16* Vb = vt + (size_t)(h * HD) * S_LEN;     // [64][S]

  bf16* const A = smem[0];
  bf16* const B = smem[1];

  const int Lt   = causal ? (qi + 1) : (S_LEN / 64);  // total 64-key tiles
  const int half = (Lt + 1) >> 1;
  const int jt0  = ck ? half : 0;
  const int jt1  = ck ? Lt : half;

  const int wrmin = qbase + qh * 32;   // wave's min q-row
  const int wrmax = wrmin + 31;        // wave's max q-row
  const int q_g   = wrmin + l31;       // this lane's q-row

  // ---- prologue: DMA K[jt0]->A, V[jt0]->B; Q gathered straight to regs ----
  if (jt0 < jt1) {
#pragma unroll
    for (int i = 0; i < 2; i++) {
      int ch = wave * 2 + i;
      int trow = ch * 8 + trl;
      gload_lds16(Kb + (size_t)(jt0 * 64 + trow) * 2048 + cgl, A + ch * 512);
      gload_lds16(Vb + (size_t)trow * S_LEN + jt0 * 64 + cgl, B + ch * 512);
    }
  }
  short8 qf[4];
#pragma unroll
  for (int kd = 0; kd < 4; kd++)
    qf[kd] = *(const short8*)(Qb + (size_t)q_g * 2048 + kd * 16 + hi * 8);

  f32x16 oacc[2];
#pragma unroll
  for (int nc = 0; nc < 2; nc++)
#pragma unroll
    for (int e = 0; e < 16; e++) oacc[nc][e] = 0.f;
  float l_st = 0.f;

  __syncthreads();  // drains prologue DMA

  for (int jt = jt0; jt < jt1; jt++) {
    const int kbase = jt * 64;
    const int kh32 = kbase + kh * 32;               // wave's key-half base
    const bool live = !(causal && kh32 > wrmax);    // wave-uniform

    uint32_t pw[2][4];  // PV A-frag words: [16-k chunk within half][word]
    if (live) {
      // ---- S^T = K Q^T for this wave's 32x32 quadrant (K from A) ----
      f32x16 sacc;
#pragma unroll
      for (int e = 0; e < 16; e++) sacc[e] = 0.f;
      __builtin_amdgcn_s_setprio(1);
#pragma unroll
      for (int kd = 0; kd < 4; kd++) {
        short8 kf = *(const short8*)(A + rot_idx(kh * 32 + l31, kd * 16 + hi * 8));
        sacc = __builtin_amdgcn_mfma_f32_32x32x16_bf16(kf, qf[kd], sacc, 0, 0, 0);
      }
      __builtin_amdgcn_s_setprio(0);
      // lane holds S[q = q_g][k = kh32 + 8g + 4hi + r]; fused
      // exp2 -> causal mask -> psum -> bf16 pair-pack.
      const bool nm = causal && (kh32 + 31 > wrmin);
      uint32_t pku[4][2];
      float psum = 0.f;
#pragma unroll
      for (int g = 0; g < 4; g++) {
#pragma unroll
        for (int h2 = 0; h2 < 2; h2++) {
          float v0 = __builtin_amdgcn_exp2f(sacc[g * 4 + h2 * 2]);
          float v1 = __builtin_amdgcn_exp2f(sacc[g * 4 + h2 * 2 + 1]);
          if (nm) {
            int kg = kh32 + g * 8 + hi * 4 + h2 * 2;
            if (kg > q_g)     v0 = 0.f;
            if (kg + 1 > q_g) v1 = 0.f;
          }
          psum += v0 + v1;
          pku[g][h2] = pack2(v0, v1);
        }
      }
      l_st += psum;
      // permlane32_swap interleaves the lane halves to build the 32x32x16
      // A-fragment entirely on the VALU.
#pragma unroll
      for (int c2 = 0; c2 < 2; c2++) {
#pragma unroll
        for (int h2 = 0; h2 < 2; h2++) {
          uint2u sw = __builtin_amdgcn_permlane32_swap(
              pku[2 * c2][h2], pku[2 * c2 + 1][h2], false, false);
          pw[c2][h2]     = sw[0];
          pw[c2][2 + h2] = sw[1];
        }
      }
    }

    __syncthreads();  // all waves done reading A (K[jt]); V[jt] DMA drained

    if (jt + 1 < jt1) {  // refill A with K[jt+1] while PV reads B
      const int kb2 = kbase + 64;
#pragma unroll
      for (int i = 0; i < 2; i++) {
        int ch = wave * 2 + i;
        int trow = ch * 8 + trl;
        gload_lds16(Kb + (size_t)(kb2 + trow) * 2048 + cgl, A + ch * 512);
      }
    }

    if (live) {
      // ---- O += P V over this wave's key-half (V from B) ----
      __builtin_amdgcn_s_setprio(1);
#pragma unroll
      for (int c2 = 0; c2 < 2; c2++) {
        if (causal && (kh32 + c2 * 16 > wrmax)) continue;  // masked chunk
        union { short8 s; uint32_t u[4]; } pf;
#pragma unroll
        for (int w = 0; w < 4; w++) pf.u[w] = pw[c2][w];
#pragma unroll
        for (int nc = 0; nc < 2; nc++) {
          short8 vf = *(const short8*)(B +
              rot_idx(nc * 32 + l31, (kh * 2 + c2) * 16 + hi * 8));
          oacc[nc] = __builtin_amdgcn_mfma_f32_32x32x16_bf16(pf.s, vf, oacc[nc], 0, 0, 0);
        }
      }
      __builtin_amdgcn_s_setprio(0);
    }

    __syncthreads();  // all waves done reading B (V[jt]); K[jt+1] DMA drained

    if (jt + 1 < jt1) {  // refill B with V[jt+1]; drains at next barrier
      const int kb2 = kbase + 64;
#pragma unroll
      for (int i = 0; i < 2; i++) {
        int ch = wave * 2 + i;
        int trow = ch * 8 + trl;
        gload_lds16(Vb + (size_t)trow * S_LEN + kb2 + cgl, B + ch * 512);
      }
    }
  }

  // ---- block-internal kh combine through (dead) LDS (v11 pattern) ----
  float ltot = l_st + __shfl_xor(l_st, 32);   // sum over hi (disjoint keys)
  float* obuf = (float*)smem;                 // 16KB: [qh][2048]
  if (kh == 1) {
    float* ob = obuf + qh * 2048;
#pragma unroll
    for (int nc = 0; nc < 2; nc++)
#pragma unroll
      for (int e = 0; e < 16; e++)
        ob[(nc * 16 + e) * 64 + lane] = oacc[nc][e];
    if (hi == 0) lbuf[qh * 32 + l31] = ltot;
  }
  __syncthreads();
  if (kh == 0) {
    float* ob = obuf + qh * 2048;
#pragma unroll
    for (int nc = 0; nc < 2; nc++)
#pragma unroll
      for (int e = 0; e < 16; e++)
        oacc[nc][e] += ob[(nc * 16 + e) * 64 + lane];
    ltot += lbuf[qh * 32 + l31];

    // ---- publish partial l (f32) into the first 4 rows of this tile's
    // region of attn_out (row qbase + ck*2 + qh, cols [h*64, h*64+64) =
    // exactly 32 floats). Disjoint across (ck, qh); merge re-reads then
    // overwrites. Kernel boundary provides ordering+coherence.
    if (hi == 0) {
      float* lrow = (float*)(attn_out +
          (size_t)(qbase + ck * 2 + qh) * DMODEL + h * HD);
      lrow[l31] = ltot;
    }
    // ---- publish partial O (bf16 [64][64], q-major) ----
    bf16* po = (ck ? p1 : p0) + (size_t)(h * 64 + qi) * 4096;
#pragma unroll
    for (int nc = 0; nc < 2; nc++)
#pragma unroll
      for (int g = 0; g < 4; g++)
#pragma unroll
        for (int r = 0; r < 4; r++)
          po[(qh * 32 + g * 8 + hi * 4 + r) * 64 + nc * 32 + l31] =
              (bf16)oacc[nc][g * 4 + r];
  }
}

// ---------------------------------------------------------------------------
// Merge kernel: per (h, qi) tile, read both l-halves (from the tile's first
// 4 rows) + both bf16 O-partials, normalize, write the final bf16 tile.
// ---------------------------------------------------------------------------
__global__ __launch_bounds__(256)
void attn_merge(const bf16* __restrict__ p0, const bf16* __restrict__ p1,
                bf16* __restrict__ attn_out) {
  const int qi = blockIdx.x;    // 0..63
  const int h  = blockIdx.y;    // 0..15
  const int tid = threadIdx.x;
  const int qbase = qi * 64;
  __shared__ float lsh[128];    // [ck*64 + q]
  if (tid < 128) {
    int ckv  = tid >> 6;
    int qhv  = (tid >> 5) & 1;
    int l31v = tid & 31;
    const float* lrow = (const float*)(attn_out +
        (size_t)(qbase + ckv * 2 + qhv) * DMODEL + h * HD);
    lsh[ckv * 64 + qhv * 32 + l31v] = lrow[l31v];
  }
  __syncthreads();

  const int q  = tid >> 2;           // 0..63
  const int d0 = (tid & 3) * 16;     // 0,16,32,48
  const float linv = 1.0f / fmaxf(lsh[q] + lsh[64 + q], 1e-30f);
  const size_t slot = (size_t)(h * 64 + qi) * 4096 + q * 64 + d0;
  short8 x0 = *(const short8*)(p0 + slot);
  short8 x1 = *(const short8*)(p0 + slot + 8);
  short8 y0 = *(const short8*)(p1 + slot);
  short8 y1 = *(const short8*)(p1 + slot + 8);
  uint32_t w[8];
#pragma unroll
  for (int j = 0; j < 4; j++) {
    float a = (b2f(x0[2 * j])     + b2f(y0[2 * j]))     * linv;
    float b = (b2f(x0[2 * j + 1]) + b2f(y0[2 * j + 1])) * linv;
    w[j] = pack2(a, b);
  }
#pragma unroll
  for (int j = 0; j < 4; j++) {
    float a = (b2f(x1[2 * j])     + b2f(y1[2 * j]))     * linv;
    float b = (b2f(x1[2 * j + 1]) + b2f(y1[2 * j + 1])) * linv;
    w[4 + j] = pack2(a, b);
  }
  bf16* outp = attn_out + (size_t)(qbase + q) * DMODEL + h * HD + d0;
  *(uint4*)(outp)     = (uint4){w[0], w[1], w[2], w[3]};
  *(uint4*)(outp + 8) = (uint4){w[4], w[5], w[6], w[7]};
}

// ---------------------------------------------------------------------------
extern "C" void kernel_launch(void* const* d_in, const int* in_sizes, int n_in,
                              void* d_out, int out_size, void* d_ws, size_t ws_size,
                              hipStream_t stream) {
  const float* x     = (const float*)d_in[0];
  const float* w_qkv = (const float*)d_in[1];
  const float* b_qkv = (const float*)d_in[2];
  const float* w_o   = (const float*)d_in[3];
  const float* b_o   = (const float*)d_in[4];
  const int*   cm    = (const int*)d_in[5];

  char* ws = (char*)d_ws;
  bf16* qkv2 = (bf16*)ws;                         // [4096][2048] Q|K (Q pre-scaled)
  bf16* vt   = (bf16*)(ws + 16777216);            // [16][64][4096] V^T per head
  bf16* attn = (bf16*)(ws + 25165824);            // [4096][1024]
  bf16* xb   = (bf16*)(ws + 33554432);            // [4096][1024]
  bf16* wqb  = (bf16*)(ws + 41943040);            // [3072][1024]
  bf16* wob  = (bf16*)(ws + 48234496);            // [1024][1024] (end 50331648)

  // attn partials live in d_out (16MB, dead during attn+merge; gemm_oproj
  // overwrites every element afterwards): ck0 -> [0,8MB), ck1 -> [8,16MB).
  bf16* p0 = (bf16*)d_out;
  bf16* p1 = (bf16*)d_out + 4194304;

  dim3 blk(256);
  const bool fast = (ws_size >= (size_t)50331648);

  if (fast) {
    const int ntot = S_LEN * DMODEL + 3 * DMODEL * DMODEL + DMODEL * DMODEL;
    cvt_all<<<dim3((ntot / 4 + 255) / 256), blk, 0, stream>>>(
        x, w_qkv, w_o, xb, wqb, wob);
    gemm_qkv<<<dim3(3 * DMODEL / 128, S_LEN / 128), blk, 0, stream>>>(
        xb, wqb, b_qkv, qkv2, vt);
    attn_kernel<<<dim3(128, NH), blk, 0, stream>>>(qkv2, vt, attn, cm, p0, p1);
    attn_merge<<<dim3(64, NH), blk, 0, stream>>>(p0, p1, attn);
    gemm_oproj<<<dim3(DMODEL / 64, S_LEN / 128), blk, 0, stream>>>(
        attn, wob, b_o, (float*)d_out);
  } else {
    gemm_qkv_f32<<<dim3(3 * DMODEL / 128, S_LEN / 128), blk, 0, stream>>>(
        x, w_qkv, b_qkv, qkv2, vt);
    attn_kernel<<<dim3(128, NH), blk, 0, stream>>>(qkv2, vt, attn, cm, p0, p1);
    attn_merge<<<dim3(64, NH), blk, 0, stream>>>(p0, p1, attn);
    gemm_oproj_f32w<<<dim3(DMODEL / 128, S_LEN / 128), blk, 0, stream>>>(
        attn, w_o, b_o, (float*)d_out);
  }
}